// Round 12
// baseline (173.674 us; speedup 1.0000x reference)
//
#include <hip/hip_runtime.h>

#define NF 160
#define NP 80
#define ND 64
#define NC 512
#define NV 81                  // stored v columns 0..80 (Hermitian half)
#define NPIXH (NF*NV)          // 12960
#define NPIXP 13056            // padded: 1632*8
#define NSTR 1632              // pixel stripes (grid.x of k_cand)
#define STRIPE 8               // pixels per stripe
#define RECQ 21                // float4 planes per pixel record
#define TWO_PI 6.283185307179586f

// per-pixel precomputed parameter slots (for k_amin_ifftu)
#define IP_AR 0
#define IP_AI 1
#define IP_BR 2
#define IP_BI 3
#define IP_P  4
#define IP_Q  5
#define IP_R  6
#define IP_C2T 7
#define IP_S2T 8
#define IP_K  9
#define NPRM 10

__device__ __forceinline__ void rot(float& c, float& s, float stc, float sts) {
  float t1 = s * sts;
  float t2 = s * stc;
  float cn = fmaf(c, stc, -t1);
  s = fmaf(c, sts, t2);
  c = cn;
}

__device__ __forceinline__ void start_i_pow(int n, float& c, float& s) {
  switch (n & 3) {
    case 0: c = 1.f; s = 0.f; break;
    case 1: c = 0.f; s = 1.f; break;
    case 2: c = -1.f; s = 0.f; break;
    default: c = 0.f; s = -1.f; break;
  }
}

// K1: T[d][a][v] = sum_b yw[d,a,b] * e^{-2pi i v (b-40)/160}, v in 0..80
__global__ __launch_bounds__(256) void k_fft_x(const float* __restrict__ patch,
                                               const float* __restrict__ gw,
                                               float2* __restrict__ T) {
  int idx = blockIdx.x * 256 + threadIdx.x;   // ND*NP*NV = 414720
  int v = idx % NV;
  int a = (idx / NV) % NP;
  int d = idx / (NV * NP);
  float c, s;
  start_i_pow(v, c, s);
  float stc, sts;
  sincosf(-TWO_PI * (float)v / (float)NF, &sts, &stc);
  const float* prow = patch + (size_t)(d * NP + a) * NP;
  const float* grow = gw + a * NP;
  float accR = 0.f, accI = 0.f;
#pragma unroll 4
  for (int b = 0; b < NP; ++b) {
    float f = prow[b] * grow[b];
    accR = fmaf(f, c, accR);
    accI = fmaf(f, s, accI);
    rot(c, s, stc, sts);
  }
  T[idx] = make_float2(accR, accI);
}

// K2: Y[d][u][v] = sum_a T[d][a][v] * e^{-2pi i u (a-40)/160}
__global__ __launch_bounds__(256) void k_fft_y(const float2* __restrict__ T,
                                               float2* __restrict__ Y) {
  int idx = blockIdx.x * 256 + threadIdx.x;   // 64*40*81 = 207360
  int v = idx % NV;
  int ug = (idx / NV) % 40;
  int d = idx / (NV * 40);
  float c[4], s[4], aR[4], aI[4], stc[4], sts[4];
#pragma unroll
  for (int j = 0; j < 4; ++j) {
    int u = ug * 4 + j;
    start_i_pow(u, c[j], s[j]);
    sincosf(-TWO_PI * (float)u / (float)NF, &sts[j], &stc[j]);
    aR[j] = 0.f; aI[j] = 0.f;
  }
  const float2* Tb = T + (size_t)(d * NP) * NV + v;
#pragma unroll 4
  for (int a = 0; a < NP; ++a) {
    float2 t = Tb[(size_t)a * NV];
#pragma unroll
    for (int j = 0; j < 4; ++j) {
      aR[j] = fmaf(t.x, c[j], aR[j]);
      aR[j] = fmaf(-t.y, s[j], aR[j]);
      aI[j] = fmaf(t.x, s[j], aI[j]);
      aI[j] = fmaf(t.y, c[j], aI[j]);
      rot(c[j], s[j], stc[j], sts[j]);
    }
  }
#pragma unroll
  for (int j = 0; j < 4; ++j) {
    int u = ug * 4 + j;
    Y[((size_t)d * NF + u) * NV + v] = make_float2(aR[j], aI[j]);
  }
}

// K3: per-pixel moments -> SoA record planes rec4[q][p], q = 0..20:
//   q0..15 = (yk[2j], yk[63-2j], yk[2j+1], yk[62-2j])
//   q16 = (Ar,Ai,Br,Bi)  q17 = (Pm,Qm,Rm,S0)  q18 = (c2t,s2t,k,wgt)
//   q19 = (cd0,sd0,cd1,sd1)  q20 = (tcd,0,0,0)
__global__ __launch_bounds__(256) void k_prep(const float2* __restrict__ Y,
                                              const float* __restrict__ delays,
                                              const float* __restrict__ kloss,
                                              const float* __restrict__ theta,
                                              float4* __restrict__ rec4,
                                              float* __restrict__ prm) {
  int p = blockIdx.x * 256 + threadIdx.x;     // 51*256 = 13056
  if (p >= NPIXH) {
#pragma unroll
    for (int jj = 0; jj < 16; ++jj)
      rec4[(size_t)jj * NPIXP + p] = make_float4(0.f, 0.f, 0.f, 0.f);
    rec4[(size_t)16 * NPIXP + p] = make_float4(0.f, 0.f, 0.f, 0.f);
    rec4[(size_t)17 * NPIXP + p] = make_float4(1.f, 0.f, 1.f, 0.f);
    rec4[(size_t)18 * NPIXP + p] = make_float4(0.f, 0.f, 0.f, 0.f);
    rec4[(size_t)19 * NPIXP + p] = make_float4(1.f, 0.f, 1.f, 0.f);
    rec4[(size_t)20 * NPIXP + p] = make_float4(2.f, 0.f, 0.f, 0.f);
    prm[IP_AR * NPIXP + p] = 0.f;  prm[IP_AI * NPIXP + p] = 0.f;
    prm[IP_BR * NPIXP + p] = 0.f;  prm[IP_BI * NPIXP + p] = 0.f;
    prm[IP_P * NPIXP + p] = 1.f;   prm[IP_Q * NPIXP + p] = 0.f;
    prm[IP_R * NPIXP + p] = 1.f;   prm[IP_C2T * NPIXP + p] = 0.f;
    prm[IP_S2T * NPIXP + p] = 0.f; prm[IP_K * NPIXP + p] = 0.f;
    return;
  }
  int u = p / NV, v = p % NV;
  float k = kloss[u * NF + v];
  float th = theta[((u + 80) % NF) * NF + ((v + 80) % NF)];
  float c2t = cosf(2.f * th), s2t = sinf(2.f * th);
  float w;
  if (v == 0 || v == 80) {
    if (u == 0 || u == 80) w = 1.f;
    else if (u < 80) w = 2.f;
    else w = 0.f;
  } else w = 2.f;
  float d0 = delays[0], d1 = delays[1];
  float sd0f, cd0f;
  sincosf(k * d0, &sd0f, &cd0f);
  float stc, sts;
  sincosf(k * (d1 - d0), &sts, &stc);
  float tcd = 2.f * stc;
  float cd = cd0f, sd = sd0f;
  float cd1s = 0.f, sd1s = 0.f;
  float Ar = 0.f, Ai = 0.f, Br = 0.f, Bi = 0.f, Pm = 0.f, Qm = 0.f, Rm = 0.f, S0 = 0.f;
  float yktmp[ND];
#pragma unroll
  for (int d = 0; d < ND; ++d) {
    if (d == 1) { cd1s = cd; sd1s = sd; }
    float2 y = Y[((size_t)d * NF + u) * NV + v];
    Ar = fmaf(y.x, cd, Ar);  Ai = fmaf(y.y, cd, Ai);
    Br = fmaf(y.x, sd, Br);  Bi = fmaf(y.y, sd, Bi);
    Pm = fmaf(cd, cd, Pm);  Qm = fmaf(cd, sd, Qm);  Rm = fmaf(sd, sd, Rm);
    float yk = sqrtf(fmaf(y.x, y.x, y.y * y.y)) * k;
    yktmp[d] = yk;
    S0 = fmaf(yk, yk, S0);
    rot(cd, sd, stc, sts);
  }
#pragma unroll
  for (int jj = 0; jj < 16; ++jj)
    rec4[(size_t)jj * NPIXP + p] = make_float4(yktmp[2 * jj], yktmp[63 - 2 * jj],
                                               yktmp[2 * jj + 1], yktmp[62 - 2 * jj]);
  rec4[(size_t)16 * NPIXP + p] = make_float4(Ar, Ai, Br, Bi);
  rec4[(size_t)17 * NPIXP + p] = make_float4(Pm, Qm, Rm, S0);
  rec4[(size_t)18 * NPIXP + p] = make_float4(c2t, s2t, k, w);
  rec4[(size_t)19 * NPIXP + p] = make_float4(cd0f, sd0f, cd1s, sd1s);
  rec4[(size_t)20 * NPIXP + p] = make_float4(tcd, 0.f, 0.f, 0.f);
  prm[IP_AR * NPIXP + p] = Ar;   prm[IP_AI * NPIXP + p] = Ai;
  prm[IP_BR * NPIXP + p] = Br;   prm[IP_BI * NPIXP + p] = Bi;
  prm[IP_P * NPIXP + p] = Pm;    prm[IP_Q * NPIXP + p] = Qm;
  prm[IP_R * NPIXP + p] = Rm;    prm[IP_C2T * NPIXP + p] = c2t;
  prm[IP_S2T * NPIXP + p] = s2t; prm[IP_K * NPIXP + p] = k;
}

// K4: hot kernel — candidate-per-lane, 8-pixel stripe staged to LDS (2.7KB),
// private accumulator, no shuffles. grid (1632, 2) = 3264 blocks.
__global__ __launch_bounds__(256) void k_cand(const float4* __restrict__ rec4,
                                              const float* __restrict__ cand,
                                              float* __restrict__ partial) {
  __shared__ float4 buf[STRIPE][RECQ];        // 2688 B
  int t = threadIdx.x;
  int c = blockIdx.y * 256 + t;               // candidate owned by this thread
  int p0 = blockIdx.x * STRIPE;               // 1632*8 = 13056 exactly
  float dc = cand[c * 3 + 0], xx = cand[c * 3 + 1], yy = cand[c * 3 + 2];
  if (t < STRIPE * RECQ) {                    // 168 staging threads
    int px = t / RECQ, q = t - px * RECQ;
    buf[px][q] = rec4[(size_t)q * NPIXP + (p0 + px)];
  }
  __syncthreads();
  float acc = 0.f;
#pragma unroll
  for (int i = 0; i < STRIPE; ++i) {
    const float4* r = &buf[i][0];
    float4 pA = r[16];                        // Ar,Ai,Br,Bi
    float4 pB = r[17];                        // Pm,Qm,Rm,S0
    float4 pC = r[18];                        // c2t,s2t,k,wgt
    float4 pD = r[19];                        // cd0,sd0,cd1,sd1
    float tcd = r[20].x;
    float w_ = fmaf(xx, pC.x, fmaf(yy, pC.y, dc));
    float sw, cw;
    __sincosf(pC.z * w_, &sw, &cw);
    float rr = fmaf(cw, pA.x, sw * pA.z);
    float ri = fmaf(cw, pA.y, sw * pA.w);
    float lhs = fmaf(cw * cw, pB.x, fmaf(2.f * cw * sw, pB.y, sw * sw * pB.z));
    float rabs = __builtin_amdgcn_sqrtf(fmaf(rr, rr, ri * ri));
    float rl = __builtin_amdgcn_rcpf(lhs);
    float e = fmaf(-lhs, rl, 1.f);
    rl = fmaf(rl, e, rl);                     // refined 1/lhs
    float kX = pC.z * rabs * rl;
    float F0 = fmaf(kX * kX, lhs, pB.w);      // contrib = F0 + F1*M
    float F1 = -2.f * kX;
    float t0 = pD.x * cw, u0 = pD.y * sw;
    float t1 = pD.z * cw, u1 = pD.w * sw;
    float A0 = t0 + u0, B0 = t0 - u0;         // cos(k d0 -/+ kw)
    float A1 = t1 + u1, B1 = t1 - u1;         // cos(k d1 -/+ kw)
    float4 y0 = r[0];
    float M0 = y0.x * fabsf(A0);
    float M1 = y0.y * fabsf(B0);
    M0 = fmaf(y0.z, fabsf(A1), M0);
    M1 = fmaf(y0.w, fabsf(B1), M1);
#pragma unroll
    for (int jj = 1; jj < 16; ++jj) {
      float4 yk = r[jj];
      float An = fmaf(tcd, A1, -A0);
      float Bn = fmaf(tcd, B1, -B0);
      M0 = fmaf(yk.x, fabsf(An), M0);
      M1 = fmaf(yk.y, fabsf(Bn), M1);
      float An2 = fmaf(tcd, An, -A1);
      float Bn2 = fmaf(tcd, Bn, -B1);
      M0 = fmaf(yk.z, fabsf(An2), M0);
      M1 = fmaf(yk.w, fabsf(Bn2), M1);
      A0 = An; A1 = An2; B0 = Bn; B1 = Bn2;
    }
    float contrib = fmaf(F1, M0 + M1, F0);
    acc = fmaf(contrib, pC.w, acc);           // *= wgt, accumulate over pixels
  }
  partial[(size_t)blockIdx.x * NC + c] = acc; // coalesced across candidates
}

// K4b: loss[c] = sum over stripes (fixed order, deterministic)
__global__ __launch_bounds__(64) void k_sum(const float* __restrict__ partial,
                                            float* __restrict__ loss) {
  int c = blockIdx.x * 64 + threadIdx.x;      // 8 blocks x 64
  float s = 0.f;
#pragma unroll 8
  for (int j = 0; j < NSTR; ++j) s += partial[(size_t)j * NC + c];
  loss[c] = s;
}

// K5: fused redundant argmin (per block) + ifft_u row DFT (blocks 0..159)
__global__ __launch_bounds__(256) void k_amin_ifftu(const float* __restrict__ loss,
                                                    const float* __restrict__ prm,
                                                    const float* __restrict__ cand,
                                                    float* __restrict__ out,
                                                    float2* __restrict__ G) {
  __shared__ float sl[256];
  __shared__ int si[256];
  __shared__ float xr[NF], xi[NF];
  int c1 = threadIdx.x, c2 = threadIdx.x + 256;
  float s1 = loss[c1], s2 = loss[c2];
  float l; int i;
  if (s2 < s1) { l = s2; i = c2; } else { l = s1; i = c1; }
  sl[threadIdx.x] = l; si[threadIdx.x] = i;
  __syncthreads();
  for (int off = 128; off > 0; off >>= 1) {
    if (threadIdx.x < off) {
      float l2 = sl[threadIdx.x + off]; int i2 = si[threadIdx.x + off];
      if (l2 < sl[threadIdx.x] || (l2 == sl[threadIdx.x] && i2 < si[threadIdx.x])) {
        sl[threadIdx.x] = l2; si[threadIdx.x] = i2;
      }
    }
    __syncthreads();
  }
  int bi = si[0];
  if (blockIdx.x == 0 && threadIdx.x == 0) {
    out[6400] = cand[bi * 3 + 0];
    out[6401] = cand[bi * 3 + 1];
    out[6402] = cand[bi * 3 + 2];
    out[6403] = sl[0] * (1.f / 1638400.f);
  }
  int u = blockIdx.x;
  float dc = cand[bi * 3 + 0], xx = cand[bi * 3 + 1], yy = cand[bi * 3 + 2];
  int v = threadIdx.x;
  if (v < NF) {
    float sign = 1.f;
    int ph;
    if (v <= 80) {
      ph = u * NV + v;
    } else {
      int u2 = (NF - u) % NF;
      ph = u2 * NV + (NF - v);
      sign = -1.f;
    }
    float Ar = prm[IP_AR * NPIXP + ph], Ai = prm[IP_AI * NPIXP + ph];
    float Br = prm[IP_BR * NPIXP + ph], Bi = prm[IP_BI * NPIXP + ph];
    float Pm = prm[IP_P * NPIXP + ph], Qm = prm[IP_Q * NPIXP + ph], Rm = prm[IP_R * NPIXP + ph];
    float c2t = prm[IP_C2T * NPIXP + ph], s2t = prm[IP_S2T * NPIXP + ph];
    float k = prm[IP_K * NPIXP + ph];
    float w_ = fmaf(xx, c2t, fmaf(yy, s2t, dc));
    float sw, cw;
    sincosf(k * w_, &sw, &cw);
    float rr = fmaf(cw, Ar, sw * Br);
    float ri = fmaf(cw, Ai, sw * Bi);
    float lhs = fmaf(cw * cw, Pm, fmaf(2.f * cw * sw, Qm, sw * sw * Rm));
    xr[v] = rr / lhs;
    xi[v] = sign * ri / lhs;
  }
  __syncthreads();
  int b = threadIdx.x;
  if (b < NP) {
    int xb = (b + 120) % NF;
    float stc, sts;
    sincosf(TWO_PI * (float)xb / (float)NF, &sts, &stc);
    float c = 1.f, s = 0.f, accR = 0.f, accI = 0.f;
#pragma unroll 4
    for (int vv = 0; vv < NF; ++vv) {
      float xrv = xr[vv], xiv = xi[vv];
      accR = fmaf(xrv, c, accR); accR = fmaf(-xiv, s, accR);
      accI = fmaf(xrv, s, accI); accI = fmaf(xiv, c, accI);
      rot(c, s, stc, sts);
    }
    G[(size_t)u * NP + b] = make_float2(accR, accI);
  }
}

// K6: ifft_y — out[a][b] = Re(sum_u G[u][b] e^{+2pi i ya u/160})/25600
__global__ __launch_bounds__(64) void k_ifft_y(const float2* __restrict__ G,
                                               float* __restrict__ out) {
  int idx = blockIdx.x * 64 + threadIdx.x;    // 6400
  int b = idx % NP;
  int a = idx / NP;
  int ya = (a + 120) % NF;
  float stc, sts;
  sincosf(TWO_PI * (float)ya / (float)NF, &sts, &stc);
  float c = 1.f, s = 0.f, accR = 0.f;
#pragma unroll 4
  for (int u = 0; u < NF; ++u) {
    float2 g = G[(size_t)u * NP + b];
    accR = fmaf(g.x, c, accR);
    accR = fmaf(-g.y, s, accR);
    rot(c, s, stc, sts);
  }
  out[idx] = accR * (1.f / 25600.f);
}

extern "C" void kernel_launch(void* const* d_in, const int* in_sizes, int n_in,
                              void* d_out, int out_size, void* d_ws, size_t ws_size,
                              hipStream_t stream) {
  (void)in_sizes; (void)n_in; (void)out_size; (void)ws_size;
  const float* patch  = (const float*)d_in[0];
  const float* gw     = (const float*)d_in[1];
  const float* delays = (const float*)d_in[2];
  const float* theta  = (const float*)d_in[4];
  const float* kloss  = (const float*)d_in[5];
  const float* cand   = (const float*)d_in[6];
  float* out = (float*)d_out;

  char* ws = (char*)d_ws;
  size_t off = 0;
  float2* Y = (float2*)(ws + off);      off += (size_t)ND * NF * NV * 8;     // 6,635,520
  float2* T = (float2*)(ws + off);      off += (size_t)ND * NP * NV * 8;     // 3,317,760
  float4* rec4 = (float4*)(ws + off);   off += (size_t)RECQ * NPIXP * 16;    // 4,386,816
  float* prm = (float*)(ws + off);      off += (size_t)NPRM * NPIXP * 4;     //   522,240
  float* partial = (float*)(ws + off);  off += (size_t)NSTR * NC * 4;        // 3,342,336
  float* loss = (float*)(ws + off);     off += (size_t)NC * 4;               //     2,048
  float2* G = (float2*)(ws + off);      off += (size_t)NF * NP * 8;          //   102,400

  hipLaunchKernelGGL(k_fft_x, dim3((ND * NP * NV) / 256), dim3(256), 0, stream, patch, gw, T);
  hipLaunchKernelGGL(k_fft_y, dim3((ND * 40 * NV) / 256), dim3(256), 0, stream, T, Y);
  hipLaunchKernelGGL(k_prep, dim3(NPIXP / 256), dim3(256), 0, stream, Y, delays, kloss, theta, rec4, prm);
  hipLaunchKernelGGL(k_cand, dim3(NSTR, 2), dim3(256), 0, stream, rec4, cand, partial);
  hipLaunchKernelGGL(k_sum, dim3(8), dim3(64), 0, stream, partial, loss);
  hipLaunchKernelGGL(k_amin_ifftu, dim3(NF), dim3(256), 0, stream, loss, prm, cand, out, G);
  hipLaunchKernelGGL(k_ifft_y, dim3(100), dim3(64), 0, stream, G, out);
}

// Round 13
// 105.277 us; speedup vs baseline: 1.6497x; 1.6497x over previous
//
#include <hip/hip_runtime.h>

#define NF 160
#define NP 80
#define ND 64
#define NC 512
#define NV 81                  // stored v columns 0..80 (Hermitian half)
#define NPIXH (NF*NV)          // 12960
#define NPIXP 13056            // padded: 1632*8
#define NSTR 1632              // pixel stripes (grid.x of k_cand)
#define STRIPE 8               // pixels per stripe
#define RECQ 21                // float4 planes per pixel record
#define BT 128                 // k_cand block threads
#define CPT 4                  // candidates per thread (128*4 = 512 = NC)
#define TWO_PI 6.283185307179586f

// per-pixel precomputed parameter slots (for k_amin_ifftu)
#define IP_AR 0
#define IP_AI 1
#define IP_BR 2
#define IP_BI 3
#define IP_P  4
#define IP_Q  5
#define IP_R  6
#define IP_C2T 7
#define IP_S2T 8
#define IP_K  9
#define NPRM 10

__device__ __forceinline__ void rot(float& c, float& s, float stc, float sts) {
  float t1 = s * sts;
  float t2 = s * stc;
  float cn = fmaf(c, stc, -t1);
  s = fmaf(c, sts, t2);
  c = cn;
}

__device__ __forceinline__ void start_i_pow(int n, float& c, float& s) {
  switch (n & 3) {
    case 0: c = 1.f; s = 0.f; break;
    case 1: c = 0.f; s = 1.f; break;
    case 2: c = -1.f; s = 0.f; break;
    default: c = 0.f; s = -1.f; break;
  }
}

// K1: T[d][a][v] = sum_b yw[d,a,b] * e^{-2pi i v (b-40)/160}, v in 0..80
__global__ __launch_bounds__(256) void k_fft_x(const float* __restrict__ patch,
                                               const float* __restrict__ gw,
                                               float2* __restrict__ T) {
  int idx = blockIdx.x * 256 + threadIdx.x;   // ND*NP*NV = 414720
  int v = idx % NV;
  int a = (idx / NV) % NP;
  int d = idx / (NV * NP);
  float c, s;
  start_i_pow(v, c, s);
  float stc, sts;
  sincosf(-TWO_PI * (float)v / (float)NF, &sts, &stc);
  const float* prow = patch + (size_t)(d * NP + a) * NP;
  const float* grow = gw + a * NP;
  float accR = 0.f, accI = 0.f;
#pragma unroll 4
  for (int b = 0; b < NP; ++b) {
    float f = prow[b] * grow[b];
    accR = fmaf(f, c, accR);
    accI = fmaf(f, s, accI);
    rot(c, s, stc, sts);
  }
  T[idx] = make_float2(accR, accI);
}

// K2: Y[d][u][v] = sum_a T[d][a][v] * e^{-2pi i u (a-40)/160}
__global__ __launch_bounds__(256) void k_fft_y(const float2* __restrict__ T,
                                               float2* __restrict__ Y) {
  int idx = blockIdx.x * 256 + threadIdx.x;   // 64*40*81 = 207360
  int v = idx % NV;
  int ug = (idx / NV) % 40;
  int d = idx / (NV * 40);
  float c[4], s[4], aR[4], aI[4], stc[4], sts[4];
#pragma unroll
  for (int j = 0; j < 4; ++j) {
    int u = ug * 4 + j;
    start_i_pow(u, c[j], s[j]);
    sincosf(-TWO_PI * (float)u / (float)NF, &sts[j], &stc[j]);
    aR[j] = 0.f; aI[j] = 0.f;
  }
  const float2* Tb = T + (size_t)(d * NP) * NV + v;
#pragma unroll 4
  for (int a = 0; a < NP; ++a) {
    float2 t = Tb[(size_t)a * NV];
#pragma unroll
    for (int j = 0; j < 4; ++j) {
      aR[j] = fmaf(t.x, c[j], aR[j]);
      aR[j] = fmaf(-t.y, s[j], aR[j]);
      aI[j] = fmaf(t.x, s[j], aI[j]);
      aI[j] = fmaf(t.y, c[j], aI[j]);
      rot(c[j], s[j], stc[j], sts[j]);
    }
  }
#pragma unroll
  for (int j = 0; j < 4; ++j) {
    int u = ug * 4 + j;
    Y[((size_t)d * NF + u) * NV + v] = make_float2(aR[j], aI[j]);
  }
}

// K3: per-pixel moments -> SoA record planes rec4[q][p], q = 0..20:
//   q0..15 = (yk[2j], yk[63-2j], yk[2j+1], yk[62-2j])
//   q16 = (Ar,Ai,Br,Bi)  q17 = (Pm,Qm,Rm,S0)  q18 = (c2t,s2t,k,wgt)
//   q19 = (cd0,sd0,cd1,sd1)  q20 = (tcd,0,0,0)
__global__ __launch_bounds__(256) void k_prep(const float2* __restrict__ Y,
                                              const float* __restrict__ delays,
                                              const float* __restrict__ kloss,
                                              const float* __restrict__ theta,
                                              float4* __restrict__ rec4,
                                              float* __restrict__ prm) {
  int p = blockIdx.x * 256 + threadIdx.x;     // 51*256 = 13056
  if (p >= NPIXH) {
#pragma unroll
    for (int jj = 0; jj < 16; ++jj)
      rec4[(size_t)jj * NPIXP + p] = make_float4(0.f, 0.f, 0.f, 0.f);
    rec4[(size_t)16 * NPIXP + p] = make_float4(0.f, 0.f, 0.f, 0.f);
    rec4[(size_t)17 * NPIXP + p] = make_float4(1.f, 0.f, 1.f, 0.f);
    rec4[(size_t)18 * NPIXP + p] = make_float4(0.f, 0.f, 0.f, 0.f);
    rec4[(size_t)19 * NPIXP + p] = make_float4(1.f, 0.f, 1.f, 0.f);
    rec4[(size_t)20 * NPIXP + p] = make_float4(2.f, 0.f, 0.f, 0.f);
    prm[IP_AR * NPIXP + p] = 0.f;  prm[IP_AI * NPIXP + p] = 0.f;
    prm[IP_BR * NPIXP + p] = 0.f;  prm[IP_BI * NPIXP + p] = 0.f;
    prm[IP_P * NPIXP + p] = 1.f;   prm[IP_Q * NPIXP + p] = 0.f;
    prm[IP_R * NPIXP + p] = 1.f;   prm[IP_C2T * NPIXP + p] = 0.f;
    prm[IP_S2T * NPIXP + p] = 0.f; prm[IP_K * NPIXP + p] = 0.f;
    return;
  }
  int u = p / NV, v = p % NV;
  float k = kloss[u * NF + v];
  float th = theta[((u + 80) % NF) * NF + ((v + 80) % NF)];
  float c2t = cosf(2.f * th), s2t = sinf(2.f * th);
  float w;
  if (v == 0 || v == 80) {
    if (u == 0 || u == 80) w = 1.f;
    else if (u < 80) w = 2.f;
    else w = 0.f;
  } else w = 2.f;
  float d0 = delays[0], d1 = delays[1];
  float sd0f, cd0f;
  sincosf(k * d0, &sd0f, &cd0f);
  float stc, sts;
  sincosf(k * (d1 - d0), &sts, &stc);
  float tcd = 2.f * stc;
  float cd = cd0f, sd = sd0f;
  float cd1s = 0.f, sd1s = 0.f;
  float Ar = 0.f, Ai = 0.f, Br = 0.f, Bi = 0.f, Pm = 0.f, Qm = 0.f, Rm = 0.f, S0 = 0.f;
  float yktmp[ND];
#pragma unroll
  for (int d = 0; d < ND; ++d) {
    if (d == 1) { cd1s = cd; sd1s = sd; }
    float2 y = Y[((size_t)d * NF + u) * NV + v];
    Ar = fmaf(y.x, cd, Ar);  Ai = fmaf(y.y, cd, Ai);
    Br = fmaf(y.x, sd, Br);  Bi = fmaf(y.y, sd, Bi);
    Pm = fmaf(cd, cd, Pm);  Qm = fmaf(cd, sd, Qm);  Rm = fmaf(sd, sd, Rm);
    float yk = sqrtf(fmaf(y.x, y.x, y.y * y.y)) * k;
    yktmp[d] = yk;
    S0 = fmaf(yk, yk, S0);
    rot(cd, sd, stc, sts);
  }
#pragma unroll
  for (int jj = 0; jj < 16; ++jj)
    rec4[(size_t)jj * NPIXP + p] = make_float4(yktmp[2 * jj], yktmp[63 - 2 * jj],
                                               yktmp[2 * jj + 1], yktmp[62 - 2 * jj]);
  rec4[(size_t)16 * NPIXP + p] = make_float4(Ar, Ai, Br, Bi);
  rec4[(size_t)17 * NPIXP + p] = make_float4(Pm, Qm, Rm, S0);
  rec4[(size_t)18 * NPIXP + p] = make_float4(c2t, s2t, k, w);
  rec4[(size_t)19 * NPIXP + p] = make_float4(cd0f, sd0f, cd1s, sd1s);
  rec4[(size_t)20 * NPIXP + p] = make_float4(tcd, 0.f, 0.f, 0.f);
  prm[IP_AR * NPIXP + p] = Ar;   prm[IP_AI * NPIXP + p] = Ai;
  prm[IP_BR * NPIXP + p] = Br;   prm[IP_BI * NPIXP + p] = Bi;
  prm[IP_P * NPIXP + p] = Pm;    prm[IP_Q * NPIXP + p] = Qm;
  prm[IP_R * NPIXP + p] = Rm;    prm[IP_C2T * NPIXP + p] = c2t;
  prm[IP_S2T * NPIXP + p] = s2t; prm[IP_K * NPIXP + p] = k;
}

// K4: hot kernel — CPT=4 candidates per thread, 128-thread block covers all
// 512 candidates; each LDS record read feeds 4 Chebyshev chains (jj-outer,
// ci-inner). LDS pipe demand drops 4x vs 1-cand-per-thread.
__global__ __launch_bounds__(BT) void k_cand(const float4* __restrict__ rec4,
                                             const float* __restrict__ cand,
                                             float* __restrict__ partial) {
  __shared__ float4 buf[STRIPE][RECQ];        // 2688 B
  int t = threadIdx.x;
  int p0 = blockIdx.x * STRIPE;               // 1632*8 = 13056 exactly
  float dc[CPT], xx[CPT], yy[CPT], acc[CPT];
#pragma unroll
  for (int ci = 0; ci < CPT; ++ci) {
    int c = t + ci * BT;
    dc[ci] = cand[c * 3 + 0];
    xx[ci] = cand[c * 3 + 1];
    yy[ci] = cand[c * 3 + 2];
    acc[ci] = 0.f;
  }
  for (int q = t; q < STRIPE * RECQ; q += BT) {   // 168 chunks, 2 rounds
    int px = q / RECQ, qq = q - px * RECQ;
    buf[px][qq] = rec4[(size_t)qq * NPIXP + (p0 + px)];
  }
  __syncthreads();
#pragma unroll
  for (int i = 0; i < STRIPE; ++i) {
    const float4* r = &buf[i][0];
    float4 pA = r[16];                        // Ar,Ai,Br,Bi
    float4 pB = r[17];                        // Pm,Qm,Rm,S0
    float4 pC = r[18];                        // c2t,s2t,k,wgt
    float4 pD = r[19];                        // cd0,sd0,cd1,sd1
    float tcd = r[20].x;
    float4 y0 = r[0];
    float A0[CPT], A1[CPT], B0[CPT], B1[CPT], M[CPT], F0[CPT], F1[CPT];
#pragma unroll
    for (int ci = 0; ci < CPT; ++ci) {
      float w_ = fmaf(xx[ci], pC.x, fmaf(yy[ci], pC.y, dc[ci]));
      float sw, cw;
      __sincosf(pC.z * w_, &sw, &cw);
      float rr = fmaf(cw, pA.x, sw * pA.z);
      float ri = fmaf(cw, pA.y, sw * pA.w);
      float lhs = fmaf(cw * cw, pB.x, fmaf(2.f * cw * sw, pB.y, sw * sw * pB.z));
      float rabs = __builtin_amdgcn_sqrtf(fmaf(rr, rr, ri * ri));
      float rl = __builtin_amdgcn_rcpf(lhs);
      float e = fmaf(-lhs, rl, 1.f);
      rl = fmaf(rl, e, rl);                   // refined 1/lhs
      float kX = pC.z * rabs * rl;
      F0[ci] = fmaf(kX * kX, lhs, pB.w);      // contrib = F0 + F1*M
      F1[ci] = -2.f * kX;
      float t0 = pD.x * cw, u0 = pD.y * sw;
      float t1 = pD.z * cw, u1 = pD.w * sw;
      A0[ci] = t0 + u0;  B0[ci] = t0 - u0;    // cos(k d0 -/+ kw)
      A1[ci] = t1 + u1;  B1[ci] = t1 - u1;    // cos(k d1 -/+ kw)
      float m = y0.x * fabsf(A0[ci]);
      m = fmaf(y0.y, fabsf(B0[ci]), m);
      m = fmaf(y0.z, fabsf(A1[ci]), m);
      m = fmaf(y0.w, fabsf(B1[ci]), m);
      M[ci] = m;
    }
#pragma unroll
    for (int jj = 1; jj < 16; ++jj) {
      float4 yk = r[jj];                      // one LDS read -> 4 chains
#pragma unroll
      for (int ci = 0; ci < CPT; ++ci) {
        float An = fmaf(tcd, A1[ci], -A0[ci]);
        float Bn = fmaf(tcd, B1[ci], -B0[ci]);
        float m = fmaf(yk.x, fabsf(An), M[ci]);
        m = fmaf(yk.y, fabsf(Bn), m);
        float An2 = fmaf(tcd, An, -A1[ci]);
        float Bn2 = fmaf(tcd, Bn, -B1[ci]);
        m = fmaf(yk.z, fabsf(An2), m);
        m = fmaf(yk.w, fabsf(Bn2), m);
        M[ci] = m;
        A0[ci] = An; A1[ci] = An2;
        B0[ci] = Bn; B1[ci] = Bn2;
      }
    }
#pragma unroll
    for (int ci = 0; ci < CPT; ++ci)
      acc[ci] = fmaf(fmaf(F1[ci], M[ci], F0[ci]), pC.w, acc[ci]);
  }
#pragma unroll
  for (int ci = 0; ci < CPT; ++ci)
    partial[(size_t)blockIdx.x * NC + t + ci * BT] = acc[ci];
}

// K4b: loss[c] = sum over stripes — one block per candidate, parallel loads,
// deterministic LDS tree reduction.
__global__ __launch_bounds__(256) void k_sum(const float* __restrict__ partial,
                                             float* __restrict__ loss) {
  __shared__ float red[256];
  int c = blockIdx.x;                         // 512 blocks
  float s = 0.f;
  for (int j = threadIdx.x; j < NSTR; j += 256)
    s += partial[(size_t)j * NC + c];
  red[threadIdx.x] = s;
  __syncthreads();
  for (int off = 128; off > 0; off >>= 1) {
    if (threadIdx.x < off) red[threadIdx.x] += red[threadIdx.x + off];
    __syncthreads();
  }
  if (threadIdx.x == 0) loss[c] = red[0];
}

// K5: fused redundant argmin (per block) + ifft_u row DFT (blocks 0..159)
__global__ __launch_bounds__(256) void k_amin_ifftu(const float* __restrict__ loss,
                                                    const float* __restrict__ prm,
                                                    const float* __restrict__ cand,
                                                    float* __restrict__ out,
                                                    float2* __restrict__ G) {
  __shared__ float sl[256];
  __shared__ int si[256];
  __shared__ float xr[NF], xi[NF];
  int c1 = threadIdx.x, c2 = threadIdx.x + 256;
  float s1 = loss[c1], s2 = loss[c2];
  float l; int i;
  if (s2 < s1) { l = s2; i = c2; } else { l = s1; i = c1; }
  sl[threadIdx.x] = l; si[threadIdx.x] = i;
  __syncthreads();
  for (int off = 128; off > 0; off >>= 1) {
    if (threadIdx.x < off) {
      float l2 = sl[threadIdx.x + off]; int i2 = si[threadIdx.x + off];
      if (l2 < sl[threadIdx.x] || (l2 == sl[threadIdx.x] && i2 < si[threadIdx.x])) {
        sl[threadIdx.x] = l2; si[threadIdx.x] = i2;
      }
    }
    __syncthreads();
  }
  int bi = si[0];
  if (blockIdx.x == 0 && threadIdx.x == 0) {
    out[6400] = cand[bi * 3 + 0];
    out[6401] = cand[bi * 3 + 1];
    out[6402] = cand[bi * 3 + 2];
    out[6403] = sl[0] * (1.f / 1638400.f);
  }
  int u = blockIdx.x;
  float dc = cand[bi * 3 + 0], xx = cand[bi * 3 + 1], yy = cand[bi * 3 + 2];
  int v = threadIdx.x;
  if (v < NF) {
    float sign = 1.f;
    int ph;
    if (v <= 80) {
      ph = u * NV + v;
    } else {
      int u2 = (NF - u) % NF;
      ph = u2 * NV + (NF - v);
      sign = -1.f;
    }
    float Ar = prm[IP_AR * NPIXP + ph], Ai = prm[IP_AI * NPIXP + ph];
    float Br = prm[IP_BR * NPIXP + ph], Bi = prm[IP_BI * NPIXP + ph];
    float Pm = prm[IP_P * NPIXP + ph], Qm = prm[IP_Q * NPIXP + ph], Rm = prm[IP_R * NPIXP + ph];
    float c2t = prm[IP_C2T * NPIXP + ph], s2t = prm[IP_S2T * NPIXP + ph];
    float k = prm[IP_K * NPIXP + ph];
    float w_ = fmaf(xx, c2t, fmaf(yy, s2t, dc));
    float sw, cw;
    sincosf(k * w_, &sw, &cw);
    float rr = fmaf(cw, Ar, sw * Br);
    float ri = fmaf(cw, Ai, sw * Bi);
    float lhs = fmaf(cw * cw, Pm, fmaf(2.f * cw * sw, Qm, sw * sw * Rm));
    xr[v] = rr / lhs;
    xi[v] = sign * ri / lhs;
  }
  __syncthreads();
  int b = threadIdx.x;
  if (b < NP) {
    int xb = (b + 120) % NF;
    float stc, sts;
    sincosf(TWO_PI * (float)xb / (float)NF, &sts, &stc);
    float c = 1.f, s = 0.f, accR = 0.f, accI = 0.f;
#pragma unroll 4
    for (int vv = 0; vv < NF; ++vv) {
      float xrv = xr[vv], xiv = xi[vv];
      accR = fmaf(xrv, c, accR); accR = fmaf(-xiv, s, accR);
      accI = fmaf(xrv, s, accI); accI = fmaf(xiv, c, accI);
      rot(c, s, stc, sts);
    }
    G[(size_t)u * NP + b] = make_float2(accR, accI);
  }
}

// K6: ifft_y — out[a][b] = Re(sum_u G[u][b] e^{+2pi i ya u/160})/25600
__global__ __launch_bounds__(64) void k_ifft_y(const float2* __restrict__ G,
                                               float* __restrict__ out) {
  int idx = blockIdx.x * 64 + threadIdx.x;    // 6400
  int b = idx % NP;
  int a = idx / NP;
  int ya = (a + 120) % NF;
  float stc, sts;
  sincosf(TWO_PI * (float)ya / (float)NF, &sts, &stc);
  float c = 1.f, s = 0.f, accR = 0.f;
#pragma unroll 4
  for (int u = 0; u < NF; ++u) {
    float2 g = G[(size_t)u * NP + b];
    accR = fmaf(g.x, c, accR);
    accR = fmaf(-g.y, s, accR);
    rot(c, s, stc, sts);
  }
  out[idx] = accR * (1.f / 25600.f);
}

extern "C" void kernel_launch(void* const* d_in, const int* in_sizes, int n_in,
                              void* d_out, int out_size, void* d_ws, size_t ws_size,
                              hipStream_t stream) {
  (void)in_sizes; (void)n_in; (void)out_size; (void)ws_size;
  const float* patch  = (const float*)d_in[0];
  const float* gw     = (const float*)d_in[1];
  const float* delays = (const float*)d_in[2];
  const float* theta  = (const float*)d_in[4];
  const float* kloss  = (const float*)d_in[5];
  const float* cand   = (const float*)d_in[6];
  float* out = (float*)d_out;

  char* ws = (char*)d_ws;
  size_t off = 0;
  float2* Y = (float2*)(ws + off);      off += (size_t)ND * NF * NV * 8;     // 6,635,520
  float2* T = (float2*)(ws + off);      off += (size_t)ND * NP * NV * 8;     // 3,317,760
  float4* rec4 = (float4*)(ws + off);   off += (size_t)RECQ * NPIXP * 16;    // 4,386,816
  float* prm = (float*)(ws + off);      off += (size_t)NPRM * NPIXP * 4;     //   522,240
  float* partial = (float*)(ws + off);  off += (size_t)NSTR * NC * 4;        // 3,342,336
  float* loss = (float*)(ws + off);     off += (size_t)NC * 4;               //     2,048
  float2* G = (float2*)(ws + off);      off += (size_t)NF * NP * 8;          //   102,400

  hipLaunchKernelGGL(k_fft_x, dim3((ND * NP * NV) / 256), dim3(256), 0, stream, patch, gw, T);
  hipLaunchKernelGGL(k_fft_y, dim3((ND * 40 * NV) / 256), dim3(256), 0, stream, T, Y);
  hipLaunchKernelGGL(k_prep, dim3(NPIXP / 256), dim3(256), 0, stream, Y, delays, kloss, theta, rec4, prm);
  hipLaunchKernelGGL(k_cand, dim3(NSTR), dim3(BT), 0, stream, rec4, cand, partial);
  hipLaunchKernelGGL(k_sum, dim3(NC), dim3(256), 0, stream, partial, loss);
  hipLaunchKernelGGL(k_amin_ifftu, dim3(NF), dim3(256), 0, stream, loss, prm, cand, out, G);
  hipLaunchKernelGGL(k_ifft_y, dim3(100), dim3(64), 0, stream, G, out);
}